// Round 4
// baseline (901.085 us; speedup 1.0000x reference)
//
#include <hip/hip_runtime.h>

// B=8, Q=100, HW=16384, D=256, H=8, hd=32, FF=2048
#define SCALE 0.17677669529663687f               // 1/sqrt(32)
#define SCALE2 (0.17677669529663687f * 1.4426950408889634f)  // 1/sqrt(32) * log2(e)

typedef __attribute__((ext_vector_type(8))) short frag8;   // 8 bf16 (A/B operand)
typedef __attribute__((ext_vector_type(4))) float facc4;   // 4 f32 (C/D)

#define MFMA16(a, b, c) __builtin_amdgcn_mfma_f32_16x16x32_bf16((a), (b), (c), 0, 0, 0)

__device__ __forceinline__ unsigned short f2b(float f) {
  union { float f; unsigned u; } v; v.f = f;
  return (unsigned short)((v.u + 0x7fffu + ((v.u >> 16) & 1u)) >> 16);
}
__device__ __forceinline__ float b2f(unsigned short h) {
  union { unsigned u; float f; } v; v.u = ((unsigned)h) << 16;
  return v.f;
}
__device__ __forceinline__ unsigned int pack2(float a, float b) {
  return (unsigned int)f2b(a) | ((unsigned int)f2b(b) << 16);
}
// truncating bf16 pack (~0.4% rel err, fine for P / pix intermediates)
__device__ __forceinline__ unsigned int tpack(float a, float b) {
  union { float f; unsigned u; } x, y; x.f = a; y.f = b;
  return (x.u >> 16) | (y.u & 0xffff0000u);
}

union F8U { frag8 f; unsigned u[4]; };

// ---------- MFMA GEMM: C[M,N](fp32) = A[M,K]fp32 @ W[N,K]fp32^T (inline bf16) ----------
template <int RELU, int BIAS>
__global__ __launch_bounds__(256) void mfma_gemm(const float* __restrict__ A,
                                                 const float* __restrict__ W,
                                                 const float* __restrict__ bias,
                                                 float* __restrict__ C,
                                                 int M, int N, int Ktot, int Kchunk) {
  __shared__ unsigned short As[64 * 40];
  __shared__ unsigned short Bs[64 * 32];
  const int t = threadIdx.x;
  const int mb = blockIdx.x, nb = blockIdx.y, zb = blockIdx.z;
  const int w = t >> 6, lane = t & 63, quad = lane >> 4, l16 = lane & 15;
  const int kbeg = zb * Kchunk;
  float* Cz = C + (size_t)zb * M * N;
  facc4 acc[4] = {};
  for (int k0 = kbeg; k0 < kbeg + Kchunk; k0 += 32) {
    {
      int r = t >> 2, c = (t & 3) * 8;
      int gr = mb * 64 + r;
      float4 f0 = {}, f1 = {};
      if (gr < M) {
        const float* src = A + (size_t)gr * Ktot + k0 + c;
        f0 = *(const float4*)src; f1 = *(const float4*)(src + 4);
      }
      uint4 p;
      p.x = pack2(f0.x, f0.y); p.y = pack2(f0.z, f0.w);
      p.z = pack2(f1.x, f1.y); p.w = pack2(f1.z, f1.w);
      *(uint4*)&As[r * 40 + c] = p;
    }
    {
      int r = t >> 2, c = (t & 3) * 8;
      const float* src = W + (size_t)(nb * 64 + r) * Ktot + k0 + c;
      float4 f0 = *(const float4*)src, f1 = *(const float4*)(src + 4);
      uint4 p;
      p.x = pack2(f0.x, f0.y); p.y = pack2(f0.z, f0.w);
      p.z = pack2(f1.x, f1.y); p.w = pack2(f1.z, f1.w);
      *(uint4*)&Bs[r * 32 + c] = p;
    }
    __syncthreads();
    frag8 af = *(const frag8*)(As + (w * 16 + l16) * 40 + quad * 8);
#pragma unroll
    for (int nt = 0; nt < 4; ++nt) {
      frag8 bf = *(const frag8*)(Bs + (nt * 16 + l16) * 32 + quad * 8);
      acc[nt] = MFMA16(af, bf, acc[nt]);
    }
    __syncthreads();
  }
#pragma unroll
  for (int nt = 0; nt < 4; ++nt)
#pragma unroll
    for (int rg = 0; rg < 4; ++rg) {
      int row = mb * 64 + w * 16 + quad * 4 + rg;
      int col = nb * 64 + nt * 16 + l16;
      if (row < M) {
        float v = acc[nt][rg] + (BIAS ? bias[col] : 0.f);
        if (RELU) v = fmaxf(v, 0.f);
        Cz[(size_t)row * N + col] = v;
      }
    }
}

// ---------- 4-partial sum + bias + residual + LayerNorm (ffn2 splitK combine) ----------
__global__ __launch_bounds__(256) void res_ln4(const float* __restrict__ p,
                                               const float* __restrict__ bias,
                                               const float* __restrict__ resid,
                                               const float* __restrict__ g,
                                               const float* __restrict__ bv,
                                               float* __restrict__ out) {
  const int r = blockIdx.x, t = threadIdx.x;
  size_t i = (size_t)r * 256 + t;
  float v = p[i] + p[i + 204800] + p[i + 409600] + p[i + 614400] + bias[t] + resid[i];
  __shared__ float red[8];
  float s1 = v, s2 = v * v;
#pragma unroll
  for (int off = 1; off < 64; off <<= 1) { s1 += __shfl_xor(s1, off, 64); s2 += __shfl_xor(s2, off, 64); }
  if ((t & 63) == 0) { red[t >> 6] = s1; red[4 + (t >> 6)] = s2; }
  __syncthreads();
  float S1 = red[0] + red[1] + red[2] + red[3];
  float S2 = red[4] + red[5] + red[6] + red[7];
  float mu = S1 * (1.f / 256.f);
  float var = S2 * (1.f / 256.f) - mu * mu;
  float inv = rsqrtf(var + 1e-5f);
  out[i] = (v - mu) * inv * g[t] + bv[t];
}

// ---------- self-attention (S=100, no mask), one wave per (b,h,q) row ----------
__global__ __launch_bounds__(256) void self_attn(const float* __restrict__ qkv,
                                                 float* __restrict__ out) {
  const int wid = blockIdx.x * 4 + (threadIdx.x >> 6);
  const int lane = threadIdx.x & 63;
  const int bh = wid / 100, q = wid - bh * 100;
  const int b = bh >> 3, h = bh & 7;
  float4 qv[8];
  {
    const float4* qr = (const float4*)(qkv + (size_t)(b * 100 + q) * 768 + h * 32);
#pragma unroll
    for (int i = 0; i < 8; ++i) {
      float4 x = qr[i];
      qv[i] = make_float4(x.x * SCALE, x.y * SCALE, x.z * SCALE, x.w * SCALE);
    }
  }
  float l = 0.f;
  float4 O[8] = {};
  for (int k0 = 0; k0 < 128; k0 += 64) {
    int k = k0 + lane;
    int kc = (k < 100) ? k : 0;
    const float4* kr = (const float4*)(qkv + (size_t)(b * 100 + kc) * 768 + 256 + h * 32);
    float s = 0.f;
#pragma unroll
    for (int i = 0; i < 8; ++i) {
      float4 kx = kr[i];
      s += qv[i].x * kx.x + qv[i].y * kx.y + qv[i].z * kx.z + qv[i].w * kx.w;
    }
    float p = (k < 100) ? __expf(s) : 0.f;
    l += p;
    const float4* vr = (const float4*)(qkv + (size_t)(b * 100 + kc) * 768 + 512 + h * 32);
#pragma unroll
    for (int i = 0; i < 8; ++i) {
      float4 vx = vr[i];
      O[i].x += p * vx.x; O[i].y += p * vx.y; O[i].z += p * vx.z; O[i].w += p * vx.w;
    }
  }
#pragma unroll
  for (int off = 1; off < 64; off <<= 1) {
    l += __shfl_xor(l, off, 64);
#pragma unroll
    for (int i = 0; i < 8; ++i) {
      O[i].x += __shfl_xor(O[i].x, off, 64);
      O[i].y += __shfl_xor(O[i].y, off, 64);
      O[i].z += __shfl_xor(O[i].z, off, 64);
      O[i].w += __shfl_xor(O[i].w, off, 64);
    }
  }
  if (lane < 32) {
    float inv = 1.f / l;
    int i4 = lane >> 2, sub = lane & 3;
    float ov = 0.f;
#pragma unroll
    for (int i = 0; i < 8; ++i) {
      if (i4 == i) {
        float4 vv = O[i];
        ov = (sub == 0) ? vv.x : (sub == 1) ? vv.y : (sub == 2) ? vv.z : vv.w;
      }
    }
    out[(size_t)(b * 100 + q) * 256 + h * 32 + lane] = ov * inv;
  }
}

// ---------- fused SA epilogue: out-proj + resid + LN1 -> x1; q-proj -> qc; wkv fp32->bf16 ----------
// grid 13 x 256 threads; block handles 64 rows.
__global__ __launch_bounds__(256) void sa_epi(const float* __restrict__ sao,
                                              const float* __restrict__ saow,
                                              const float* __restrict__ saob,
                                              const float* __restrict__ queries,
                                              const float* __restrict__ g1,
                                              const float* __restrict__ b1,
                                              const float* __restrict__ caqw,
                                              const float* __restrict__ caqb,
                                              const float* __restrict__ cakvw,
                                              unsigned short* __restrict__ wkvb,
                                              float* __restrict__ x1,
                                              float* __restrict__ qc) {
  __shared__ unsigned short As[64 * 40];
  __shared__ unsigned short Bs[256 * 32];
  __shared__ unsigned short Cs[64 * 264];
  __shared__ float redS[64][5];
  __shared__ float redQ[64][5];
  __shared__ float muv[64][2];
  const int t = threadIdx.x;
  const int w = t >> 6, lane = t & 63, quad = lane >> 4, l16 = lane & 15;
  const int r0 = blockIdx.x * 64;

  // convert ca kv-weights fp32 -> bf16 (spread over 13 blocks)
  for (int i = (blockIdx.x * 256 + t) * 8; i < 131072; i += 13 * 256 * 8) {
    float4 a = *(const float4*)(cakvw + i);
    float4 b = *(const float4*)(cakvw + i + 4);
    uint4 p;
    p.x = pack2(a.x, a.y); p.y = pack2(a.z, a.w);
    p.z = pack2(b.x, b.y); p.w = pack2(b.z, b.w);
    *(uint4*)(wkvb + i) = p;
  }

  // ---- GEMM1: 64x256 = sao @ saow^T
  facc4 acc[4][4] = {};
  for (int k0 = 0; k0 < 256; k0 += 32) {
    {
      int r = t >> 2, c = (t & 3) * 8;
      int gr = r0 + r;
      float4 f0 = {}, f1 = {};
      if (gr < 800) {
        const float* s = sao + (size_t)gr * 256 + k0 + c;
        f0 = *(const float4*)s; f1 = *(const float4*)(s + 4);
      }
      uint4 p;
      p.x = pack2(f0.x, f0.y); p.y = pack2(f0.z, f0.w);
      p.z = pack2(f1.x, f1.y); p.w = pack2(f1.z, f1.w);
      *(uint4*)&As[r * 40 + c] = p;
    }
    {  // B: thread t stages full row t (32 cols)
      const float* s = saow + (size_t)t * 256 + k0;
      float4 a0 = *(const float4*)s, a1 = *(const float4*)(s + 4);
      float4 a2 = *(const float4*)(s + 8), a3 = *(const float4*)(s + 12);
      float4 a4 = *(const float4*)(s + 16), a5 = *(const float4*)(s + 20);
      float4 a6 = *(const float4*)(s + 24), a7 = *(const float4*)(s + 28);
      uint4 p0, p1;
      p0.x = pack2(a0.x, a0.y); p0.y = pack2(a0.z, a0.w); p0.z = pack2(a1.x, a1.y); p0.w = pack2(a1.z, a1.w);
      p1.x = pack2(a2.x, a2.y); p1.y = pack2(a2.z, a2.w); p1.z = pack2(a3.x, a3.y); p1.w = pack2(a3.z, a3.w);
      *(uint4*)&Bs[t * 32] = p0; *(uint4*)&Bs[t * 32 + 8] = p1;
      p0.x = pack2(a4.x, a4.y); p0.y = pack2(a4.z, a4.w); p0.z = pack2(a5.x, a5.y); p0.w = pack2(a5.z, a5.w);
      p1.x = pack2(a6.x, a6.y); p1.y = pack2(a6.z, a6.w); p1.z = pack2(a7.x, a7.y); p1.w = pack2(a7.z, a7.w);
      *(uint4*)&Bs[t * 32 + 16] = p0; *(uint4*)&Bs[t * 32 + 24] = p1;
    }
    __syncthreads();
    frag8 af[4], bf[4];
#pragma unroll
    for (int mt = 0; mt < 4; ++mt) af[mt] = *(const frag8*)(As + (mt * 16 + l16) * 40 + quad * 8);
#pragma unroll
    for (int nt = 0; nt < 4; ++nt) bf[nt] = *(const frag8*)(Bs + (w * 64 + nt * 16 + l16) * 32 + quad * 8);
#pragma unroll
    for (int mt = 0; mt < 4; ++mt)
#pragma unroll
      for (int nt = 0; nt < 4; ++nt) acc[mt][nt] = MFMA16(af[mt], bf[nt], acc[mt][nt]);
    __syncthreads();
  }
  // epilogue: C + bias + resid -> Cs (bf16)
#pragma unroll
  for (int mt = 0; mt < 4; ++mt)
#pragma unroll
    for (int nt = 0; nt < 4; ++nt) {
      int col = w * 64 + nt * 16 + l16;
      float bb = saob[col];
#pragma unroll
      for (int rg = 0; rg < 4; ++rg) {
        int row = mt * 16 + quad * 4 + rg;
        int gr = r0 + row;
        float rv = (gr < 800) ? queries[(size_t)gr * 256 + col] : 0.f;
        Cs[row * 264 + col] = f2b(acc[mt][nt][rg] + bb + rv);
      }
    }
  __syncthreads();
  // LN over rows
  {
    int tr = t >> 2, seg = t & 3;
    const unsigned short* cr = &Cs[tr * 264 + seg * 64];
    float s1 = 0.f, s2 = 0.f;
#pragma unroll 8
    for (int c = 0; c < 64; ++c) { float v = b2f(cr[c]); s1 += v; s2 += v * v; }
    redS[tr][seg] = s1; redQ[tr][seg] = s2;
  }
  __syncthreads();
  if (t < 64) {
    float S1 = redS[t][0] + redS[t][1] + redS[t][2] + redS[t][3];
    float S2 = redQ[t][0] + redQ[t][1] + redQ[t][2] + redQ[t][3];
    float mu = S1 * (1.f / 256.f);
    float var = S2 * (1.f / 256.f) - mu * mu;
    muv[t][0] = mu; muv[t][1] = rsqrtf(var + 1e-5f);
  }
  __syncthreads();
  {
    int tr = t >> 2, seg = t & 3;
    float mu = muv[tr][0], inv = muv[tr][1];
    int gr = r0 + tr;
    unsigned short* cr = &Cs[tr * 264 + seg * 64];
    float* xr = x1 + (size_t)gr * 256 + seg * 64;
#pragma unroll 8
    for (int c = 0; c < 64; ++c) {
      float v = (b2f(cr[c]) - mu) * inv * g1[seg * 64 + c] + b1[seg * 64 + c];
      cr[c] = f2b(v);
      if (gr < 800) xr[c] = v;
    }
  }
  __syncthreads();
  // ---- GEMM2: qc = x1tile @ caqw^T + caqb (A from Cs, stride 264)
  facc4 acc2[4][4] = {};
  for (int k0 = 0; k0 < 256; k0 += 32) {
    {
      const float* s = caqw + (size_t)t * 256 + k0;
      float4 a0 = *(const float4*)s, a1 = *(const float4*)(s + 4);
      float4 a2 = *(const float4*)(s + 8), a3 = *(const float4*)(s + 12);
      float4 a4 = *(const float4*)(s + 16), a5 = *(const float4*)(s + 20);
      float4 a6 = *(const float4*)(s + 24), a7 = *(const float4*)(s + 28);
      uint4 p0, p1;
      p0.x = pack2(a0.x, a0.y); p0.y = pack2(a0.z, a0.w); p0.z = pack2(a1.x, a1.y); p0.w = pack2(a1.z, a1.w);
      p1.x = pack2(a2.x, a2.y); p1.y = pack2(a2.z, a2.w); p1.z = pack2(a3.x, a3.y); p1.w = pack2(a3.z, a3.w);
      *(uint4*)&Bs[t * 32] = p0; *(uint4*)&Bs[t * 32 + 8] = p1;
      p0.x = pack2(a4.x, a4.y); p0.y = pack2(a4.z, a4.w); p0.z = pack2(a5.x, a5.y); p0.w = pack2(a5.z, a5.w);
      p1.x = pack2(a6.x, a6.y); p1.y = pack2(a6.z, a6.w); p1.z = pack2(a7.x, a7.y); p1.w = pack2(a7.z, a7.w);
      *(uint4*)&Bs[t * 32 + 16] = p0; *(uint4*)&Bs[t * 32 + 24] = p1;
    }
    __syncthreads();
    frag8 af[4], bf[4];
#pragma unroll
    for (int mt = 0; mt < 4; ++mt) af[mt] = *(const frag8*)(Cs + (mt * 16 + l16) * 264 + k0 + quad * 8);
#pragma unroll
    for (int nt = 0; nt < 4; ++nt) bf[nt] = *(const frag8*)(Bs + (w * 64 + nt * 16 + l16) * 32 + quad * 8);
#pragma unroll
    for (int mt = 0; mt < 4; ++mt)
#pragma unroll
      for (int nt = 0; nt < 4; ++nt) acc2[mt][nt] = MFMA16(af[mt], bf[nt], acc2[mt][nt]);
    __syncthreads();
  }
#pragma unroll
  for (int mt = 0; mt < 4; ++mt)
#pragma unroll
    for (int nt = 0; nt < 4; ++nt) {
      int col = w * 64 + nt * 16 + l16;
      float bb = caqb[col];
#pragma unroll
      for (int rg = 0; rg < 4; ++rg) {
        int gr = r0 + mt * 16 + quad * 4 + rg;
        if (gr < 800) qc[(size_t)gr * 256 + col] = acc2[mt][nt][rg] + bb;
      }
    }
}

// ---------- fused KV-projection + masked cross-attention (round-3 verified) ----------
__global__ __launch_bounds__(512, 2) void ca_fused(const float* __restrict__ qc,
                                                   const unsigned short* __restrict__ wkv,
                                                   const float* __restrict__ bkv,
                                                   const float* __restrict__ pix,
                                                   const unsigned char* __restrict__ mask,
                                                   unsigned short* __restrict__ Opartb,
                                                   float* __restrict__ lpart) {
  const int bid = blockIdx.x;
  const int b = bid >> 5, chunk = bid & 31;
  const int t = threadIdx.x;
  const int h = t >> 6, lane = t & 63, quad = lane >> 4, l16 = lane & 15;
  const int bh = b * 8 + h;

  __shared__ unsigned short PixS[8 * 32 * 40];

  frag8 qf[7];
#pragma unroll
  for (int qt = 0; qt < 7; ++qt) {
    int r = qt * 16 + l16;
    float4 f0 = {}, f1 = {};
    if (r < 100) {
      const float* qrow = qc + (size_t)(b * 100 + r) * 256 + h * 32 + quad * 4;
      f0 = *(const float4*)qrow;
      f1 = *(const float4*)(qrow + 16);
    }
    F8U u;
    u.u[0] = pack2(f0.x * SCALE2, f0.y * SCALE2);
    u.u[1] = pack2(f0.z * SCALE2, f0.w * SCALE2);
    u.u[2] = pack2(f1.x * SCALE2, f1.y * SCALE2);
    u.u[3] = pack2(f1.z * SCALE2, f1.w * SCALE2);
    qf[qt] = u.f;
  }

  float bK[2][4], bV[2];
#pragma unroll
  for (int mf = 0; mf < 2; ++mf) {
#pragma unroll
    for (int rg = 0; rg < 4; ++rg) bK[mf][rg] = bkv[h * 32 + mf * 16 + quad * 4 + rg];
    bV[mf] = bkv[256 + h * 32 + mf * 16 + l16];
  }

  const unsigned short* wkbase = wkv + (size_t)(h * 32) * 256;
  const unsigned short* wvbase = wkv + (size_t)(256 + h * 32) * 256;

  facc4 o[7][2] = {};
  float lacc[7] = {};
  const facc4 zacc = {0.f, 0.f, 0.f, 0.f};

  for (int it = 0; it < 16; ++it) {
    const int kk = it * 32;
    const int gkey = chunk * 512 + kk;
    __syncthreads();
    {
      int row = t >> 4, cg = (t & 15) * 16;
      const float* src = pix + ((size_t)(b * 16384 + gkey + row)) * 256 + cg;
      float4 a0 = *(const float4*)src;
      float4 a1 = *(const float4*)(src + 4);
      float4 a2 = *(const float4*)(src + 8);
      float4 a3 = *(const float4*)(src + 12);
      uint4 u0, u1;
      u0.x = tpack(a0.x, a0.y); u0.y = tpack(a0.z, a0.w);
      u0.z = tpack(a1.x, a1.y); u0.w = tpack(a1.z, a1.w);
      u1.x = tpack(a2.x, a2.y); u1.y = tpack(a2.z, a2.w);
      u1.z = tpack(a3.x, a3.y); u1.w = tpack(a3.z, a3.w);
      unsigned short* d = PixS + (cg >> 5) * 1280 + row * 40 + (cg & 31);
      *(uint4*)d = u0; *(uint4*)(d + 8) = u1;
    }
    __syncthreads();

    facc4 ka[2][2] = {}, va[2][2] = {};
#pragma unroll
    for (int cb = 0; cb < 8; ++cb) {
      frag8 pf0 = *(const frag8*)(PixS + cb * 1280 + l16 * 40 + quad * 8);
      frag8 pf1 = *(const frag8*)(PixS + cb * 1280 + (16 + l16) * 40 + quad * 8);
      int co = cb * 32 + quad * 8;
      frag8 wk0 = *(const frag8*)(wkbase + (size_t)l16 * 256 + co);
      frag8 wk1 = *(const frag8*)(wkbase + (size_t)(16 + l16) * 256 + co);
      frag8 wv0 = *(const frag8*)(wvbase + (size_t)l16 * 256 + co);
      frag8 wv1 = *(const frag8*)(wvbase + (size_t)(16 + l16) * 256 + co);
      ka[0][0] = MFMA16(wk0, pf0, ka[0][0]); ka[0][1] = MFMA16(wk0, pf1, ka[0][1]);
      ka[1][0] = MFMA16(wk1, pf0, ka[1][0]); ka[1][1] = MFMA16(wk1, pf1, ka[1][1]);
      va[0][0] = MFMA16(pf0, wv0, va[0][0]); va[0][1] = MFMA16(pf0, wv1, va[0][1]);
      va[1][0] = MFMA16(pf1, wv0, va[1][0]); va[1][1] = MFMA16(pf1, wv1, va[1][1]);
    }
    frag8 kfA0, kfA1, vfB0, vfB1;
    {
      F8U k0u, k1u, v0u, v1u;
#pragma unroll
      for (int pr = 0; pr < 4; ++pr) {
        int mf = pr >> 1, r0v = (pr & 1) * 2, r1v = r0v + 1;
        k0u.u[pr] = tpack(ka[mf][0][r0v] + bK[mf][r0v], ka[mf][0][r1v] + bK[mf][r1v]);
        k1u.u[pr] = tpack(ka[mf][1][r0v] + bK[mf][r0v], ka[mf][1][r1v] + bK[mf][r1v]);
        v0u.u[pr] = tpack(va[mf][0][r0v] + bV[0], va[mf][0][r1v] + bV[0]);
        v1u.u[pr] = tpack(va[mf][1][r0v] + bV[1], va[mf][1][r1v] + bV[1]);
      }
      kfA0 = k0u.f; kfA1 = k1u.f; vfB0 = v0u.f; vfB1 = v1u.f;
    }

    const unsigned char* mbase = mask + (size_t)bh * 100 * 16384 + gkey + quad * 4;
#pragma unroll
    for (int qt = 0; qt < 7; ++qt) {
      facc4 s0 = MFMA16(kfA0, qf[qt], zacc);
      facc4 s1 = MFMA16(kfA1, qf[qt], zacc);
      int r = qt * 16 + l16;
      int rc = (r < 100) ? r : 99;
      const unsigned char* mrow = mbase + (size_t)rc * 16384;
      unsigned m0 = *(const unsigned*)mrow;
      unsigned m1 = *(const unsigned*)(mrow + 16);
      if (r >= 100) { m0 = 0; m1 = 0; }
      float p[8];
#pragma unroll
      for (int rg = 0; rg < 4; ++rg) {
        float e0 = exp2f(s0[rg]);
        float e1 = exp2f(s1[rg]);
        p[rg] = ((m0 >> (rg * 8)) & 1u) ? e0 : 0.f;
        p[4 + rg] = ((m1 >> (rg * 8)) & 1u) ? e1 : 0.f;
      }
      lacc[qt] += p[0] + p[1] + p[2] + p[3] + p[4] + p[5] + p[6] + p[7];
      F8U pu;
      pu.u[0] = tpack(p[0], p[1]); pu.u[1] = tpack(p[2], p[3]);
      pu.u[2] = tpack(p[4], p[5]); pu.u[3] = tpack(p[6], p[7]);
      o[qt][0] = MFMA16(pu.f, vfB0, o[qt][0]);
      o[qt][1] = MFMA16(pu.f, vfB1, o[qt][1]);
    }
  }

#pragma unroll
  for (int qt = 0; qt < 7; ++qt) {
    lacc[qt] += __shfl_xor(lacc[qt], 16, 64);
    lacc[qt] += __shfl_xor(lacc[qt], 32, 64);
  }
  unsigned short* Op = Opartb + ((size_t)bh * 32 + chunk) * 112 * 32;
  float* lp = lpart + ((size_t)bh * 32 + chunk) * 112;
#pragma unroll
  for (int qt = 0; qt < 7; ++qt) {
#pragma unroll
    for (int rg = 0; rg < 4; ++rg) {
      int row = qt * 16 + quad * 4 + rg;
      Op[row * 32 + l16] = f2b(o[qt][0][rg]);
      Op[row * 32 + 16 + l16] = f2b(o[qt][1][rg]);
    }
    if (lane < 16) lp[qt * 16 + lane] = lacc[qt];
  }
}

// ---------- fused CA epilogue: combine partials + out-proj + resid + LN2 -> x2 ----------
// grid 16 = (b 8) x (half 2: 50 rows each)
__global__ __launch_bounds__(256) void ca_epi(const unsigned short* __restrict__ Opartb,
                                              const float* __restrict__ lpart,
                                              const float* __restrict__ caow,
                                              const float* __restrict__ caob,
                                              const float* __restrict__ x1,
                                              const float* __restrict__ g2,
                                              const float* __restrict__ b2v,
                                              float* __restrict__ x2) {
  __shared__ unsigned short Ca[64 * 264];
  __shared__ unsigned short Bs[256 * 32];
  __shared__ float linv[8][52];
  __shared__ float redS[64][5];
  __shared__ float redQ[64][5];
  __shared__ float muv[64][2];
  const int t = threadIdx.x;
  const int w = t >> 6, lane = t & 63, quad = lane >> 4, l16 = lane & 15;
  const int b = blockIdx.x >> 1, half = blockIdx.x & 1;
  const int q0 = half * 50;
  const int gr0 = b * 100 + q0;

  // zero pad rows 50..63
  for (int i = t; i < 14 * 264; i += 256) Ca[50 * 264 + i] = 0;
  // l-sum inverses: wave w handles heads w*2 + (lane>>5); p = lane&31
  {
    int h = w * 2 + (lane >> 5), p = lane & 31;
    int bh = b * 8 + h;
    for (int r = 0; r < 50; ++r) {
      float v = lpart[((size_t)(bh * 32 + p)) * 112 + q0 + r];
      v += __shfl_xor(v, 1, 64); v += __shfl_xor(v, 2, 64);
      v += __shfl_xor(v, 4, 64); v += __shfl_xor(v, 8, 64);
      v += __shfl_xor(v, 16, 64);
      if (p == 0) linv[h][r] = 1.f / v;
    }
  }
  __syncthreads();
  // combine: thread (h = t>>5, d = t&31)
  {
    int h = t >> 5, d = t & 31;
    int bh = b * 8 + h;
    float accr[25];
#pragma unroll
    for (int pass = 0; pass < 2; ++pass) {
#pragma unroll
      for (int r = 0; r < 25; ++r) accr[r] = 0.f;
      for (int p = 0; p < 32; ++p) {
        const unsigned short* base = Opartb + ((size_t)(bh * 32 + p) * 112 + q0 + pass * 25) * 32 + d;
#pragma unroll
        for (int r = 0; r < 25; ++r) accr[r] += b2f(base[r * 32]);
      }
#pragma unroll
      for (int r = 0; r < 25; ++r)
        Ca[(pass * 25 + r) * 264 + h * 32 + d] = f2b(accr[r] * linv[h][pass * 25 + r]);
    }
  }
  __syncthreads();
  // GEMM: x2tile = Ca @ caow^T + caob + resid; LN2
  facc4 acc[4][4] = {};
  for (int k0 = 0; k0 < 256; k0 += 32) {
    {
      const float* s = caow + (size_t)t * 256 + k0;
      float4 a0 = *(const float4*)s, a1 = *(const float4*)(s + 4);
      float4 a2 = *(const float4*)(s + 8), a3 = *(const float4*)(s + 12);
      float4 a4 = *(const float4*)(s + 16), a5 = *(const float4*)(s + 20);
      float4 a6 = *(const float4*)(s + 24), a7 = *(const float4*)(s + 28);
      uint4 p0, p1;
      p0.x = pack2(a0.x, a0.y); p0.y = pack2(a0.z, a0.w); p0.z = pack2(a1.x, a1.y); p0.w = pack2(a1.z, a1.w);
      p1.x = pack2(a2.x, a2.y); p1.y = pack2(a2.z, a2.w); p1.z = pack2(a3.x, a3.y); p1.w = pack2(a3.z, a3.w);
      *(uint4*)&Bs[t * 32] = p0; *(uint4*)&Bs[t * 32 + 8] = p1;
      p0.x = pack2(a4.x, a4.y); p0.y = pack2(a4.z, a4.w); p0.z = pack2(a5.x, a5.y); p0.w = pack2(a5.z, a5.w);
      p1.x = pack2(a6.x, a6.y); p1.y = pack2(a6.z, a6.w); p1.z = pack2(a7.x, a7.y); p1.w = pack2(a7.z, a7.w);
      *(uint4*)&Bs[t * 32 + 16] = p0; *(uint4*)&Bs[t * 32 + 24] = p1;
    }
    __syncthreads();
    frag8 af[4], bf[4];
#pragma unroll
    for (int mt = 0; mt < 4; ++mt) af[mt] = *(const frag8*)(Ca + (mt * 16 + l16) * 264 + k0 + quad * 8);
#pragma unroll
    for (int nt = 0; nt < 4; ++nt) bf[nt] = *(const frag8*)(Bs + (w * 64 + nt * 16 + l16) * 32 + quad * 8);
#pragma unroll
    for (int mt = 0; mt < 4; ++mt)
#pragma unroll
      for (int nt = 0; nt < 4; ++nt) acc[mt][nt] = MFMA16(af[mt], bf[nt], acc[mt][nt]);
    __syncthreads();
  }
  // epilogue into Ca (A-tile no longer needed)
#pragma unroll
  for (int mt = 0; mt < 4; ++mt)
#pragma unroll
    for (int nt = 0; nt < 4; ++nt) {
      int col = w * 64 + nt * 16 + l16;
      float bb = caob[col];
#pragma unroll
      for (int rg = 0; rg < 4; ++rg) {
        int row = mt * 16 + quad * 4 + rg;
        float rv = (row < 50) ? x1[(size_t)(gr0 + row) * 256 + col] : 0.f;
        Ca[row * 264 + col] = f2b(acc[mt][nt][rg] + bb + rv);
      }
    }
  __syncthreads();
  {
    int tr = t >> 2, seg = t & 3;
    const unsigned short* cr = &Ca[tr * 264 + seg * 64];
    float s1 = 0.f, s2 = 0.f;
#pragma unroll 8
    for (int c = 0; c < 64; ++c) { float v = b2f(cr[c]); s1 += v; s2 += v * v; }
    redS[tr][seg] = s1; redQ[tr][seg] = s2;
  }
  __syncthreads();
  if (t < 64) {
    float S1 = redS[t][0] + redS[t][1] + redS[t][2] + redS[t][3];
    float S2 = redQ[t][0] + redQ[t][1] + redQ[t][2] + redQ[t][3];
    float mu = S1 * (1.f / 256.f);
    float var = S2 * (1.f / 256.f) - mu * mu;
    muv[t][0] = mu; muv[t][1] = rsqrtf(var + 1e-5f);
  }
  __syncthreads();
  {
    int tr = t >> 2, seg = t & 3;
    if (tr < 50) {
      float mu = muv[tr][0], inv = muv[tr][1];
      const unsigned short* cr = &Ca[tr * 264 + seg * 64];
      float* xr = x2 + (size_t)(gr0 + tr) * 256 + seg * 64;
#pragma unroll 8
      for (int c = 0; c < 64; ++c)
        xr[c] = (b2f(cr[c]) - mu) * inv * g2[seg * 64 + c] + b2v[seg * 64 + c];
    }
  }
}

// ---------- host ----------
extern "C" void kernel_launch(void* const* d_in, const int* in_sizes, int n_in,
                              void* d_out, int out_size, void* d_ws, size_t ws_size,
                              hipStream_t stream) {
  const float* queries = (const float*)d_in[0];
  const float* pix = (const float*)d_in[1];
  const unsigned char* mask = (const unsigned char*)d_in[2];
  const float* sa_in_w = (const float*)d_in[3];
  const float* sa_in_b = (const float*)d_in[4];
  const float* sa_out_w = (const float*)d_in[5];
  const float* sa_out_b = (const float*)d_in[6];
  const float* n1g = (const float*)d_in[7];
  const float* n1b = (const float*)d_in[8];
  const float* ca_in_w = (const float*)d_in[9];
  const float* ca_in_b = (const float*)d_in[10];
  const float* ca_out_w = (const float*)d_in[11];
  const float* ca_out_b = (const float*)d_in[12];
  const float* n2g = (const float*)d_in[13];
  const float* n2b = (const float*)d_in[14];
  const float* ff_w1 = (const float*)d_in[15];
  const float* ff_b1 = (const float*)d_in[16];
  const float* ff_w2 = (const float*)d_in[17];
  const float* ff_b2 = (const float*)d_in[18];
  const float* n3g = (const float*)d_in[19];
  const float* n3b = (const float*)d_in[20];
  float* out = (float*)d_out;
  char* ws = (char*)d_ws;

  float* qkvs = (float*)(ws + 0);                              // 2457600
  float* sao  = (float*)(ws + 2457600);                        // 819200
  float* x1   = (float*)(ws + 3276800);                        // 819200
  float* qc   = (float*)(ws + 4096000);                        // 819200
  float* x2   = (float*)(ws + 4915200);                        // 819200
  float* hffn = (float*)(ws + 5734400);                        // 6553600
  float* ptmp = (float*)(ws + 12288000);                       // 3276800
  unsigned short* wkvb = (unsigned short*)(ws + 15564800);     // 262144
  float* lpart = (float*)(ws + 15826944);                      // 917504
  unsigned short* Opartb = (unsigned short*)(ws + 16744448);   // 14680064

  // 1) self-attention block
  mfma_gemm<0, 1><<<dim3(13, 12, 1), 256, 0, stream>>>(queries, sa_in_w, sa_in_b, qkvs, 800, 768, 256, 256);
  self_attn<<<1600, 256, 0, stream>>>(qkvs, sao);
  sa_epi<<<13, 256, 0, stream>>>(sao, sa_out_w, sa_out_b, queries, n1g, n1b,
                                 ca_in_w, ca_in_b, ca_in_w + 65536, wkvb, x1, qc);

  // 2) masked cross-attention block
  ca_fused<<<256, 512, 0, stream>>>(qc, wkvb, ca_in_b + 256, pix, mask, Opartb, lpart);
  ca_epi<<<16, 256, 0, stream>>>(Opartb, lpart, ca_out_w, ca_out_b, x1, n2g, n2b, x2);

  // 3) FFN block
  mfma_gemm<1, 1><<<dim3(13, 32, 1), 256, 0, stream>>>(x2, ff_w1, ff_b1, hffn, 800, 2048, 256, 256);
  mfma_gemm<0, 0><<<dim3(13, 4, 4), 256, 0, stream>>>(hffn, ff_w2, nullptr, ptmp, 800, 256, 2048, 512);
  res_ln4<<<800, 256, 0, stream>>>(ptmp, ff_b2, x2, n3g, n3b, out);
}

// Round 5
// 823.574 us; speedup vs baseline: 1.0941x; 1.0941x over previous
//
#include <hip/hip_runtime.h>

// B=8, Q=100, HW=16384, D=256, H=8, hd=32, FF=2048
#define SCALE 0.17677669529663687f               // 1/sqrt(32)
#define SCALE2 (0.17677669529663687f * 1.4426950408889634f)  // 1/sqrt(32) * log2(e)

typedef __attribute__((ext_vector_type(8))) short frag8;   // 8 bf16 (A/B operand)
typedef __attribute__((ext_vector_type(4))) float facc4;   // 4 f32 (C/D)

#define MFMA16(a, b, c) __builtin_amdgcn_mfma_f32_16x16x32_bf16((a), (b), (c), 0, 0, 0)

__device__ __forceinline__ unsigned short f2b(float f) {
  union { float f; unsigned u; } v; v.f = f;
  return (unsigned short)((v.u + 0x7fffu + ((v.u >> 16) & 1u)) >> 16);
}
__device__ __forceinline__ float b2f(unsigned short h) {
  union { unsigned u; float f; } v; v.u = ((unsigned)h) << 16;
  return v.f;
}
__device__ __forceinline__ unsigned int pack2(float a, float b) {
  return (unsigned int)f2b(a) | ((unsigned int)f2b(b) << 16);
}
// truncating bf16 pack (~0.4% rel err, fine for P / pix intermediates)
__device__ __forceinline__ unsigned int tpack(float a, float b) {
  union { float f; unsigned u; } x, y; x.f = a; y.f = b;
  return (x.u >> 16) | (y.u & 0xffff0000u);
}
__device__ __forceinline__ void gl_lds16(const void* g, void* l) {
  __builtin_amdgcn_global_load_lds((const __attribute__((address_space(1))) unsigned int*)g,
                                   (__attribute__((address_space(3))) unsigned int*)l, 16, 0, 0);
}

union F8U { frag8 f; unsigned u[4]; };

// ---------- weights fp32 -> bf16, one shot ----------
__global__ __launch_bounds__(256) void cvt_weights(const float* __restrict__ s0, const float* __restrict__ s1,
                                                   const float* __restrict__ s2, const float* __restrict__ s3,
                                                   const float* __restrict__ s4, const float* __restrict__ s5,
                                                   unsigned short* __restrict__ dst) {
  int bid = blockIdx.x;
  const float* src; int off;
  if (bid < 96)       { src = s0; off = 0; }
  else if (bid < 128) { src = s1; off = 196608; bid -= 96; }
  else if (bid < 224) { src = s2; off = 262144; bid -= 128; }
  else if (bid < 256) { src = s3; off = 458752; bid -= 224; }
  else if (bid < 512) { src = s4; off = 524288; bid -= 256; }
  else                { src = s5; off = 1048576; bid -= 512; }
  int i = bid * 2048 + threadIdx.x * 8;
  float4 a = *(const float4*)(src + i);
  float4 b = *(const float4*)(src + i + 4);
  uint4 p;
  p.x = pack2(a.x, a.y); p.y = pack2(a.z, a.w);
  p.z = pack2(b.x, b.y); p.w = pack2(b.z, b.w);
  *(uint4*)(dst + off + i) = p;
}

// ---------- MFMA GEMM: C[M,N](fp32) = A[M,K]fp32 @ Wb[N,K]bf16^T (+bias, relu); splitK via blockIdx.z ----------
template <int RELU, int BIAS>
__global__ __launch_bounds__(256) void mfma_gemm(const float* __restrict__ A,
                                                 const unsigned short* __restrict__ Wb,
                                                 const float* __restrict__ bias,
                                                 float* __restrict__ C,
                                                 int M, int N, int Ktot, int Kchunk) {
  __shared__ unsigned short As[64 * 40];
  __shared__ unsigned short Bs[64 * 32];
  const int t = threadIdx.x;
  const int mb = blockIdx.x, nb = blockIdx.y, zb = blockIdx.z;
  const int w = t >> 6, lane = t & 63, quad = lane >> 4, l16 = lane & 15;
  const int kbeg = zb * Kchunk;
  float* Cz = C + (size_t)zb * M * N;
  facc4 acc[4] = {};
  for (int k0 = kbeg; k0 < kbeg + Kchunk; k0 += 32) {
    {
      int r = t >> 2, c = (t & 3) * 8;
      int gr = mb * 64 + r;
      float4 f0 = {}, f1 = {};
      if (gr < M) {
        const float* src = A + (size_t)gr * Ktot + k0 + c;
        f0 = *(const float4*)src; f1 = *(const float4*)(src + 4);
      }
      uint4 p;
      p.x = pack2(f0.x, f0.y); p.y = pack2(f0.z, f0.w);
      p.z = pack2(f1.x, f1.y); p.w = pack2(f1.z, f1.w);
      *(uint4*)&As[r * 40 + c] = p;
    }
    {
      int row = w * 16 + (lane >> 2);
      gl_lds16(Wb + (size_t)(nb * 64 + row) * Ktot + k0 + (lane & 3) * 8, Bs + w * 512);
    }
    __syncthreads();
    frag8 af = *(const frag8*)(As + (w * 16 + l16) * 40 + quad * 8);
#pragma unroll
    for (int nt = 0; nt < 4; ++nt) {
      frag8 bf = *(const frag8*)(Bs + (nt * 16 + l16) * 32 + quad * 8);
      acc[nt] = MFMA16(af, bf, acc[nt]);
    }
    __syncthreads();
  }
#pragma unroll
  for (int nt = 0; nt < 4; ++nt)
#pragma unroll
    for (int rg = 0; rg < 4; ++rg) {
      int row = mb * 64 + w * 16 + quad * 4 + rg;
      int col = nb * 64 + nt * 16 + l16;
      if (row < M) {
        float v = acc[nt][rg] + (BIAS ? bias[col] : 0.f);
        if (RELU) v = fmaxf(v, 0.f);
        Cz[(size_t)row * N + col] = v;
      }
    }
}

// ---------- residual + LayerNorm ----------
__global__ __launch_bounds__(256) void res_ln(const float* __restrict__ y,
                                              const float* __restrict__ resid,
                                              const float* __restrict__ g,
                                              const float* __restrict__ bv,
                                              float* __restrict__ out) {
  const int r = blockIdx.x, t = threadIdx.x;
  float v = y[(size_t)r * 256 + t] + resid[(size_t)r * 256 + t];
  __shared__ float red[8];
  float s1 = v, s2 = v * v;
#pragma unroll
  for (int off = 1; off < 64; off <<= 1) { s1 += __shfl_xor(s1, off, 64); s2 += __shfl_xor(s2, off, 64); }
  if ((t & 63) == 0) { red[t >> 6] = s1; red[4 + (t >> 6)] = s2; }
  __syncthreads();
  float S1 = red[0] + red[1] + red[2] + red[3];
  float S2 = red[4] + red[5] + red[6] + red[7];
  float mu = S1 * (1.f / 256.f);
  float var = S2 * (1.f / 256.f) - mu * mu;
  float inv = rsqrtf(var + 1e-5f);
  out[(size_t)r * 256 + t] = (v - mu) * inv * g[t] + bv[t];
}

// ---------- 4-partial sum + bias + residual + LayerNorm (ffn2 splitK combine) ----------
__global__ __launch_bounds__(256) void res_ln4(const float* __restrict__ p,
                                               const float* __restrict__ bias,
                                               const float* __restrict__ resid,
                                               const float* __restrict__ g,
                                               const float* __restrict__ bv,
                                               float* __restrict__ out) {
  const int r = blockIdx.x, t = threadIdx.x;
  size_t i = (size_t)r * 256 + t;
  float v = p[i] + p[i + 204800] + p[i + 409600] + p[i + 614400] + bias[t] + resid[i];
  __shared__ float red[8];
  float s1 = v, s2 = v * v;
#pragma unroll
  for (int off = 1; off < 64; off <<= 1) { s1 += __shfl_xor(s1, off, 64); s2 += __shfl_xor(s2, off, 64); }
  if ((t & 63) == 0) { red[t >> 6] = s1; red[4 + (t >> 6)] = s2; }
  __syncthreads();
  float S1 = red[0] + red[1] + red[2] + red[3];
  float S2 = red[4] + red[5] + red[6] + red[7];
  float mu = S1 * (1.f / 256.f);
  float var = S2 * (1.f / 256.f) - mu * mu;
  float inv = rsqrtf(var + 1e-5f);
  out[i] = (v - mu) * inv * g[t] + bv[t];
}

// ---------- self-attention (S=100, no mask), one wave per (b,h,q) row ----------
__global__ __launch_bounds__(256) void self_attn(const float* __restrict__ qkv,
                                                 float* __restrict__ out) {
  const int wid = blockIdx.x * 4 + (threadIdx.x >> 6);
  const int lane = threadIdx.x & 63;
  const int bh = wid / 100, q = wid - bh * 100;
  const int b = bh >> 3, h = bh & 7;
  float4 qv[8];
  {
    const float4* qr = (const float4*)(qkv + (size_t)(b * 100 + q) * 768 + h * 32);
#pragma unroll
    for (int i = 0; i < 8; ++i) {
      float4 x = qr[i];
      qv[i] = make_float4(x.x * SCALE, x.y * SCALE, x.z * SCALE, x.w * SCALE);
    }
  }
  float l = 0.f;
  float4 O[8] = {};
  for (int k0 = 0; k0 < 128; k0 += 64) {
    int k = k0 + lane;
    int kc = (k < 100) ? k : 0;
    const float4* kr = (const float4*)(qkv + (size_t)(b * 100 + kc) * 768 + 256 + h * 32);
    float s = 0.f;
#pragma unroll
    for (int i = 0; i < 8; ++i) {
      float4 kx = kr[i];
      s += qv[i].x * kx.x + qv[i].y * kx.y + qv[i].z * kx.z + qv[i].w * kx.w;
    }
    float p = (k < 100) ? __expf(s) : 0.f;
    l += p;
    const float4* vr = (const float4*)(qkv + (size_t)(b * 100 + kc) * 768 + 512 + h * 32);
#pragma unroll
    for (int i = 0; i < 8; ++i) {
      float4 vx = vr[i];
      O[i].x += p * vx.x; O[i].y += p * vx.y; O[i].z += p * vx.z; O[i].w += p * vx.w;
    }
  }
#pragma unroll
  for (int off = 1; off < 64; off <<= 1) {
    l += __shfl_xor(l, off, 64);
#pragma unroll
    for (int i = 0; i < 8; ++i) {
      O[i].x += __shfl_xor(O[i].x, off, 64);
      O[i].y += __shfl_xor(O[i].y, off, 64);
      O[i].z += __shfl_xor(O[i].z, off, 64);
      O[i].w += __shfl_xor(O[i].w, off, 64);
    }
  }
  if (lane < 32) {
    float inv = 1.f / l;
    int i4 = lane >> 2, sub = lane & 3;
    float ov = 0.f;
#pragma unroll
    for (int i = 0; i < 8; ++i) {
      if (i4 == i) {
        float4 vv = O[i];
        ov = (sub == 0) ? vv.x : (sub == 1) ? vv.y : (sub == 2) ? vv.z : vv.w;
      }
    }
    out[(size_t)(b * 100 + q) * 256 + h * 32 + lane] = ov * inv;
  }
}

// ---------- fused KV-projection + masked cross-attention, double-buffered pix staging ----------
// grid 256 = (b 8) x (chunk 32: 512 keys); block 512 = 8 waves, wave = head.
// launch_bounds(512,1): grid==CU count so 2nd residency slot was unusable; relax VGPR cap.
__global__ __launch_bounds__(512, 1) void ca_fused(const float* __restrict__ qc,
                                                   const unsigned short* __restrict__ wkv,
                                                   const float* __restrict__ bkv,
                                                   const float* __restrict__ pix,
                                                   const unsigned char* __restrict__ mask,
                                                   unsigned short* __restrict__ Opartb,
                                                   float* __restrict__ lpart) {
  const int bid = blockIdx.x;
  const int b = bid >> 5, chunk = bid & 31;
  const int t = threadIdx.x;
  const int h = t >> 6, lane = t & 63, quad = lane >> 4, l16 = lane & 15;
  const int bh = b * 8 + h;

  __shared__ unsigned short PixS[2][8 * 32 * 40];  // double-buffered [chb][key 32][40 pad]

  // per-thread staging coords (32 keys x 256 ch per slice; thread -> (row, 16-ch group))
  const int srow = t >> 4, scg = (t & 15) * 16;
  const float* psrc = pix + ((size_t)(b * 16384 + chunk * 512 + srow)) * 256 + scg;
  const int sldoff = (scg >> 5) * 1280 + srow * 40 + (scg & 31);

  // Q fragments, sigma-permuted k-slots
  frag8 qf[7];
#pragma unroll
  for (int qt = 0; qt < 7; ++qt) {
    int r = qt * 16 + l16;
    float4 f0 = {}, f1 = {};
    if (r < 100) {
      const float* qrow = qc + (size_t)(b * 100 + r) * 256 + h * 32 + quad * 4;
      f0 = *(const float4*)qrow;
      f1 = *(const float4*)(qrow + 16);
    }
    F8U u;
    u.u[0] = pack2(f0.x * SCALE2, f0.y * SCALE2);
    u.u[1] = pack2(f0.z * SCALE2, f0.w * SCALE2);
    u.u[2] = pack2(f1.x * SCALE2, f1.y * SCALE2);
    u.u[3] = pack2(f1.z * SCALE2, f1.w * SCALE2);
    qf[qt] = u.f;
  }

  float bK[2][4], bV[2];
#pragma unroll
  for (int mf = 0; mf < 2; ++mf) {
#pragma unroll
    for (int rg = 0; rg < 4; ++rg) bK[mf][rg] = bkv[h * 32 + mf * 16 + quad * 4 + rg];
    bV[mf] = bkv[256 + h * 32 + mf * 16 + l16];
  }

  const unsigned short* wkbase = wkv + (size_t)(h * 32) * 256;
  const unsigned short* wvbase = wkv + (size_t)(256 + h * 32) * 256;

  facc4 o[7][2] = {};
  float lacc[7] = {};
  const facc4 zacc = {0.f, 0.f, 0.f, 0.f};

  // preload slice 0 into buffer 0
  {
    float4 a0 = *(const float4*)psrc;
    float4 a1 = *(const float4*)(psrc + 4);
    float4 a2 = *(const float4*)(psrc + 8);
    float4 a3 = *(const float4*)(psrc + 12);
    uint4 u0, u1;
    u0.x = tpack(a0.x, a0.y); u0.y = tpack(a0.z, a0.w);
    u0.z = tpack(a1.x, a1.y); u0.w = tpack(a1.z, a1.w);
    u1.x = tpack(a2.x, a2.y); u1.y = tpack(a2.z, a2.w);
    u1.z = tpack(a3.x, a3.y); u1.w = tpack(a3.z, a3.w);
    unsigned short* d = PixS[0] + sldoff;
    *(uint4*)d = u0; *(uint4*)(d + 8) = u1;
  }
  __syncthreads();

  for (int it = 0; it < 16; ++it) {
    const int kk = it * 32;
    const int gkey = chunk * 512 + kk;

    // issue next slice's global loads early (in flight during MFMA below)
    float4 n0, n1, n2, n3;
    if (it < 15) {
      const float* s = psrc + (size_t)(it + 1) * 8192;
      n0 = *(const float4*)s;       n1 = *(const float4*)(s + 4);
      n2 = *(const float4*)(s + 8); n3 = *(const float4*)(s + 12);
    }

    const unsigned short* Pb = PixS[it & 1];

    facc4 ka[2][2] = {}, va[2][2] = {};
#pragma unroll
    for (int cb = 0; cb < 8; ++cb) {
      frag8 pf0 = *(const frag8*)(Pb + cb * 1280 + l16 * 40 + quad * 8);
      frag8 pf1 = *(const frag8*)(Pb + cb * 1280 + (16 + l16) * 40 + quad * 8);
      int co = cb * 32 + quad * 8;
      frag8 wk0 = *(const frag8*)(wkbase + (size_t)l16 * 256 + co);
      frag8 wk1 = *(const frag8*)(wkbase + (size_t)(16 + l16) * 256 + co);
      frag8 wv0 = *(const frag8*)(wvbase + (size_t)l16 * 256 + co);
      frag8 wv1 = *(const frag8*)(wvbase + (size_t)(16 + l16) * 256 + co);
      ka[0][0] = MFMA16(wk0, pf0, ka[0][0]); ka[0][1] = MFMA16(wk0, pf1, ka[0][1]);
      ka[1][0] = MFMA16(wk1, pf0, ka[1][0]); ka[1][1] = MFMA16(wk1, pf1, ka[1][1]);
      va[0][0] = MFMA16(pf0, wv0, va[0][0]); va[0][1] = MFMA16(pf0, wv1, va[0][1]);
      va[1][0] = MFMA16(pf1, wv0, va[1][0]); va[1][1] = MFMA16(pf1, wv1, va[1][1]);
    }
    frag8 kfA0, kfA1, vfB0, vfB1;
    {
      F8U k0u, k1u, v0u, v1u;
#pragma unroll
      for (int pr = 0; pr < 4; ++pr) {
        int mf = pr >> 1, r0v = (pr & 1) * 2, r1v = r0v + 1;
        k0u.u[pr] = tpack(ka[mf][0][r0v] + bK[mf][r0v], ka[mf][0][r1v] + bK[mf][r1v]);
        k1u.u[pr] = tpack(ka[mf][1][r0v] + bK[mf][r0v], ka[mf][1][r1v] + bK[mf][r1v]);
        v0u.u[pr] = tpack(va[mf][0][r0v] + bV[0], va[mf][0][r1v] + bV[0]);
        v1u.u[pr] = tpack(va[mf][1][r0v] + bV[1], va[mf][1][r1v] + bV[1]);
      }
      kfA0 = k0u.f; kfA1 = k1u.f; vfB0 = v0u.f; vfB1 = v1u.f;
    }

    const unsigned char* mbase = mask + (size_t)bh * 100 * 16384 + gkey + quad * 4;
#pragma unroll
    for (int qt = 0; qt < 7; ++qt) {
      facc4 s0 = MFMA16(kfA0, qf[qt], zacc);
      facc4 s1 = MFMA16(kfA1, qf[qt], zacc);
      int r = qt * 16 + l16;
      int rc = (r < 100) ? r : 99;
      const unsigned char* mrow = mbase + (size_t)rc * 16384;
      unsigned m0 = *(const unsigned*)mrow;
      unsigned m1 = *(const unsigned*)(mrow + 16);
      if (r >= 100) { m0 = 0; m1 = 0; }
      float p[8];
#pragma unroll
      for (int rg = 0; rg < 4; ++rg) {
        float e0 = exp2f(s0[rg]);
        float e1 = exp2f(s1[rg]);
        p[rg] = ((m0 >> (rg * 8)) & 1u) ? e0 : 0.f;
        p[4 + rg] = ((m1 >> (rg * 8)) & 1u) ? e1 : 0.f;
      }
      lacc[qt] += p[0] + p[1] + p[2] + p[3] + p[4] + p[5] + p[6] + p[7];
      F8U pu;
      pu.u[0] = tpack(p[0], p[1]); pu.u[1] = tpack(p[2], p[3]);
      pu.u[2] = tpack(p[4], p[5]); pu.u[3] = tpack(p[6], p[7]);
      o[qt][0] = MFMA16(pu.f, vfB0, o[qt][0]);
      o[qt][1] = MFMA16(pu.f, vfB1, o[qt][1]);
    }

    // write next slice into the other buffer, then single barrier
    if (it < 15) {
      uint4 u0, u1;
      u0.x = tpack(n0.x, n0.y); u0.y = tpack(n0.z, n0.w);
      u0.z = tpack(n1.x, n1.y); u0.w = tpack(n1.z, n1.w);
      u1.x = tpack(n2.x, n2.y); u1.y = tpack(n2.z, n2.w);
      u1.z = tpack(n3.x, n3.y); u1.w = tpack(n3.z, n3.w);
      unsigned short* d = PixS[1 - (it & 1)] + sldoff;
      *(uint4*)d = u0; *(uint4*)(d + 8) = u1;
    }
    __syncthreads();
  }

#pragma unroll
  for (int qt = 0; qt < 7; ++qt) {
    lacc[qt] += __shfl_xor(lacc[qt], 16, 64);
    lacc[qt] += __shfl_xor(lacc[qt], 32, 64);
  }
  unsigned short* Op = Opartb + ((size_t)bh * 32 + chunk) * 112 * 32;
  float* lp = lpart + ((size_t)bh * 32 + chunk) * 112;
#pragma unroll
  for (int qt = 0; qt < 7; ++qt) {
#pragma unroll
    for (int rg = 0; rg < 4; ++rg) {
      int row = qt * 16 + quad * 4 + rg;
      Op[row * 32 + l16] = f2b(o[qt][0][rg]);
      Op[row * 32 + 16 + l16] = f2b(o[qt][1][rg]);
    }
    if (lane < 16) lp[qt * 16 + lane] = lacc[qt];
  }
}

// ---------- combine partials: out = sum(O) / sum(l) ----------
__global__ __launch_bounds__(256) void cross_combine(const unsigned short* __restrict__ Opartb,
                                                     const float* __restrict__ lpart,
                                                     float* __restrict__ out) {
  const int bid = blockIdx.x;
  const int bh = bid / 13, qg = bid - bh * 13;
  const int t = threadIdx.x;
  const int q = qg * 8 + (t >> 5), d = t & 31;
  if (q >= 100) return;
  const int b = bh >> 3, h = bh & 7;
  float osum = 0.f, lsum = 0.f;
#pragma unroll 4
  for (int p = 0; p < 32; ++p) {
    osum += b2f(Opartb[(((size_t)bh * 32 + p) * 112 + q) * 32 + d]);
    lsum += lpart[((size_t)bh * 32 + p) * 112 + q];
  }
  out[(size_t)(b * 100 + q) * 256 + h * 32 + d] = osum / lsum;
}

// ---------- host ----------
extern "C" void kernel_launch(void* const* d_in, const int* in_sizes, int n_in,
                              void* d_out, int out_size, void* d_ws, size_t ws_size,
                              hipStream_t stream) {
  const float* queries = (const float*)d_in[0];
  const float* pix = (const float*)d_in[1];
  const unsigned char* mask = (const unsigned char*)d_in[2];
  const float* sa_in_w = (const float*)d_in[3];
  const float* sa_in_b = (const float*)d_in[4];
  const float* sa_out_w = (const float*)d_in[5];
  const float* sa_out_b = (const float*)d_in[6];
  const float* n1g = (const float*)d_in[7];
  const float* n1b = (const float*)d_in[8];
  const float* ca_in_w = (const float*)d_in[9];
  const float* ca_in_b = (const float*)d_in[10];
  const float* ca_out_w = (const float*)d_in[11];
  const float* ca_out_b = (const float*)d_in[12];
  const float* n2g = (const float*)d_in[13];
  const float* n2b = (const float*)d_in[14];
  const float* ff_w1 = (const float*)d_in[15];
  const float* ff_b1 = (const float*)d_in[16];
  const float* ff_w2 = (const float*)d_in[17];
  const float* ff_b2 = (const float*)d_in[18];
  const float* n3g = (const float*)d_in[19];
  const float* n3b = (const float*)d_in[20];
  float* out = (float*)d_out;
  char* ws = (char*)d_ws;

  unsigned short* wb   = (unsigned short*)(ws + 134217728);    // 3145728
  float* qkvs   = (float*)(ws + 152043520);                    // 2457600
  float* sao    = (float*)(ws + 154501120);                    // 819200
  float* ptmp   = (float*)(ws + 155320320);                    // 3276800 (4 splitK partials)
  float* x1     = (float*)(ws + 158597120);                    // 819200
  float* qc     = (float*)(ws + 159416320);                    // 819200
  unsigned short* Opartb = (unsigned short*)(ws + 160235520);  // 14680064 (bf16)
  float* lpart  = (float*)(ws + 189595648);                    // 917504
  float* ca_out = (float*)(ws + 190513152);                    // 819200
  float* x2     = (float*)(ws + 191332352);                    // 819200
  float* hffn   = (float*)(ws + 192151552);                    // 6553600

  const unsigned short* wb_sain  = wb;
  const unsigned short* wb_saout = wb + 196608;
  const unsigned short* wb_caq   = wb + 262144;
  const unsigned short* wb_cakv  = wb + 327680;
  const unsigned short* wb_caout = wb + 458752;
  const unsigned short* wb_ff1   = wb + 524288;
  const unsigned short* wb_ff2   = wb + 1048576;

  cvt_weights<<<768, 256, 0, stream>>>(sa_in_w, sa_out_w, ca_in_w, ca_out_w, ff_w1, ff_w2, wb);

  // 1) self-attention block
  mfma_gemm<0, 1><<<dim3(13, 12, 1), 256, 0, stream>>>(queries, wb_sain, sa_in_b, qkvs, 800, 768, 256, 256);
  self_attn<<<1600, 256, 0, stream>>>(qkvs, sao);
  mfma_gemm<0, 1><<<dim3(13, 4, 1), 256, 0, stream>>>(sao, wb_saout, sa_out_b, ptmp, 800, 256, 256, 256);
  res_ln<<<800, 256, 0, stream>>>(ptmp, queries, n1g, n1b, x1);

  // 2) masked cross-attention block (fused KV-proj + attention)
  mfma_gemm<0, 1><<<dim3(13, 4, 1), 256, 0, stream>>>(x1, wb_caq, ca_in_b, qc, 800, 256, 256, 256);
  ca_fused<<<256, 512, 0, stream>>>(qc, wb_cakv, ca_in_b + 256, pix, mask, Opartb, lpart);
  cross_combine<<<64 * 13, 256, 0, stream>>>(Opartb, lpart, ca_out);
  mfma_gemm<0, 1><<<dim3(13, 4, 1), 256, 0, stream>>>(ca_out, wb_caout, ca_out_b, ptmp, 800, 256, 256, 256);
  res_ln<<<800, 256, 0, stream>>>(ptmp, x1, n2g, n2b, x2);

  // 3) FFN block
  mfma_gemm<1, 1><<<dim3(13, 32, 1), 256, 0, stream>>>(x2, wb_ff1, ff_b1, hffn, 800, 2048, 256, 256);
  mfma_gemm<0, 0><<<dim3(13, 4, 4), 256, 0, stream>>>(hffn, wb_ff2, nullptr, ptmp, 800, 256, 2048, 512);
  res_ln4<<<800, 256, 0, stream>>>(ptmp, ff_b2, x2, n3g, n3b, out);
}

// Round 6
// 806.527 us; speedup vs baseline: 1.1172x; 1.0211x over previous
//
#include <hip/hip_runtime.h>

// B=8, Q=100, HW=16384, D=256, H=8, hd=32, FF=2048
#define SCALE 0.17677669529663687f               // 1/sqrt(32)
#define SCALE2 (0.17677669529663687f * 1.4426950408889634f)  // 1/sqrt(32) * log2(e)

typedef __attribute__((ext_vector_type(8))) short frag8;   // 8 bf16 (A/B operand)
typedef __attribute__((ext_vector_type(4))) float facc4;   // 4 f32 (C/D)

#define MFMA16(a, b, c) __builtin_amdgcn_mfma_f32_16x16x32_bf16((a), (b), (c), 0, 0, 0)

__device__ __forceinline__ unsigned short f2b(float f) {
  union { float f; unsigned u; } v; v.f = f;
  return (unsigned short)((v.u + 0x7fffu + ((v.u >> 16) & 1u)) >> 16);
}
__device__ __forceinline__ float b2f(unsigned short h) {
  union { unsigned u; float f; } v; v.u = ((unsigned)h) << 16;
  return v.f;
}
__device__ __forceinline__ unsigned int pack2(float a, float b) {
  return (unsigned int)f2b(a) | ((unsigned int)f2b(b) << 16);
}
// truncating bf16 pack (~0.4% rel err, fine for P / pix intermediates)
__device__ __forceinline__ unsigned int tpack(float a, float b) {
  union { float f; unsigned u; } x, y; x.f = a; y.f = b;
  return (x.u >> 16) | (y.u & 0xffff0000u);
}
__device__ __forceinline__ void gl_lds16(const void* g, void* l) {
  __builtin_amdgcn_global_load_lds((const __attribute__((address_space(1))) unsigned int*)g,
                                   (__attribute__((address_space(3))) unsigned int*)l, 16, 0, 0);
}

union F8U { frag8 f; unsigned u[4]; };

// ---------- weights fp32 -> bf16, one shot ----------
__global__ __launch_bounds__(256) void cvt_weights(const float* __restrict__ s0, const float* __restrict__ s1,
                                                   const float* __restrict__ s2, const float* __restrict__ s3,
                                                   const float* __restrict__ s4, const float* __restrict__ s5,
                                                   unsigned short* __restrict__ dst) {
  int bid = blockIdx.x;
  const float* src; int off;
  if (bid < 96)       { src = s0; off = 0; }
  else if (bid < 128) { src = s1; off = 196608; bid -= 96; }
  else if (bid < 224) { src = s2; off = 262144; bid -= 128; }
  else if (bid < 256) { src = s3; off = 458752; bid -= 224; }
  else if (bid < 512) { src = s4; off = 524288; bid -= 256; }
  else                { src = s5; off = 1048576; bid -= 512; }
  int i = bid * 2048 + threadIdx.x * 8;
  float4 a = *(const float4*)(src + i);
  float4 b = *(const float4*)(src + i + 4);
  uint4 p;
  p.x = pack2(a.x, a.y); p.y = pack2(a.z, a.w);
  p.z = pack2(b.x, b.y); p.w = pack2(b.z, b.w);
  *(uint4*)(dst + off + i) = p;
}

// ---------- MFMA GEMM: C[M,N](fp32) = A[M,K]fp32 @ Wb[N,K]bf16^T (+bias, relu); splitK via blockIdx.z ----------
template <int RELU, int BIAS>
__global__ __launch_bounds__(256) void mfma_gemm(const float* __restrict__ A,
                                                 const unsigned short* __restrict__ Wb,
                                                 const float* __restrict__ bias,
                                                 float* __restrict__ C,
                                                 int M, int N, int Ktot, int Kchunk) {
  __shared__ unsigned short As[64 * 40];
  __shared__ unsigned short Bs[64 * 32];
  const int t = threadIdx.x;
  const int mb = blockIdx.x, nb = blockIdx.y, zb = blockIdx.z;
  const int w = t >> 6, lane = t & 63, quad = lane >> 4, l16 = lane & 15;
  const int kbeg = zb * Kchunk;
  float* Cz = C + (size_t)zb * M * N;
  facc4 acc[4] = {};
  for (int k0 = kbeg; k0 < kbeg + Kchunk; k0 += 32) {
    {
      int r = t >> 2, c = (t & 3) * 8;
      int gr = mb * 64 + r;
      float4 f0 = {}, f1 = {};
      if (gr < M) {
        const float* src = A + (size_t)gr * Ktot + k0 + c;
        f0 = *(const float4*)src; f1 = *(const float4*)(src + 4);
      }
      uint4 p;
      p.x = pack2(f0.x, f0.y); p.y = pack2(f0.z, f0.w);
      p.z = pack2(f1.x, f1.y); p.w = pack2(f1.z, f1.w);
      *(uint4*)&As[r * 40 + c] = p;
    }
    {
      int row = w * 16 + (lane >> 2);
      gl_lds16(Wb + (size_t)(nb * 64 + row) * Ktot + k0 + (lane & 3) * 8, Bs + w * 512);
    }
    __syncthreads();
    frag8 af = *(const frag8*)(As + (w * 16 + l16) * 40 + quad * 8);
#pragma unroll
    for (int nt = 0; nt < 4; ++nt) {
      frag8 bf = *(const frag8*)(Bs + (nt * 16 + l16) * 32 + quad * 8);
      acc[nt] = MFMA16(af, bf, acc[nt]);
    }
    __syncthreads();
  }
#pragma unroll
  for (int nt = 0; nt < 4; ++nt)
#pragma unroll
    for (int rg = 0; rg < 4; ++rg) {
      int row = mb * 64 + w * 16 + quad * 4 + rg;
      int col = nb * 64 + nt * 16 + l16;
      if (row < M) {
        float v = acc[nt][rg] + (BIAS ? bias[col] : 0.f);
        if (RELU) v = fmaxf(v, 0.f);
        Cz[(size_t)row * N + col] = v;
      }
    }
}

// ---------- residual + LayerNorm ----------
__global__ __launch_bounds__(256) void res_ln(const float* __restrict__ y,
                                              const float* __restrict__ resid,
                                              const float* __restrict__ g,
                                              const float* __restrict__ bv,
                                              float* __restrict__ out) {
  const int r = blockIdx.x, t = threadIdx.x;
  float v = y[(size_t)r * 256 + t] + resid[(size_t)r * 256 + t];
  __shared__ float red[8];
  float s1 = v, s2 = v * v;
#pragma unroll
  for (int off = 1; off < 64; off <<= 1) { s1 += __shfl_xor(s1, off, 64); s2 += __shfl_xor(s2, off, 64); }
  if ((t & 63) == 0) { red[t >> 6] = s1; red[4 + (t >> 6)] = s2; }
  __syncthreads();
  float S1 = red[0] + red[1] + red[2] + red[3];
  float S2 = red[4] + red[5] + red[6] + red[7];
  float mu = S1 * (1.f / 256.f);
  float var = S2 * (1.f / 256.f) - mu * mu;
  float inv = rsqrtf(var + 1e-5f);
  out[(size_t)r * 256 + t] = (v - mu) * inv * g[t] + bv[t];
}

// ---------- 4-partial sum + bias + residual + LayerNorm (ffn2 splitK combine) ----------
__global__ __launch_bounds__(256) void res_ln4(const float* __restrict__ p,
                                               const float* __restrict__ bias,
                                               const float* __restrict__ resid,
                                               const float* __restrict__ g,
                                               const float* __restrict__ bv,
                                               float* __restrict__ out) {
  const int r = blockIdx.x, t = threadIdx.x;
  size_t i = (size_t)r * 256 + t;
  float v = p[i] + p[i + 204800] + p[i + 409600] + p[i + 614400] + bias[t] + resid[i];
  __shared__ float red[8];
  float s1 = v, s2 = v * v;
#pragma unroll
  for (int off = 1; off < 64; off <<= 1) { s1 += __shfl_xor(s1, off, 64); s2 += __shfl_xor(s2, off, 64); }
  if ((t & 63) == 0) { red[t >> 6] = s1; red[4 + (t >> 6)] = s2; }
  __syncthreads();
  float S1 = red[0] + red[1] + red[2] + red[3];
  float S2 = red[4] + red[5] + red[6] + red[7];
  float mu = S1 * (1.f / 256.f);
  float var = S2 * (1.f / 256.f) - mu * mu;
  float inv = rsqrtf(var + 1e-5f);
  out[i] = (v - mu) * inv * g[t] + bv[t];
}

// ---------- self-attention (S=100, no mask), one wave per (b,h,q) row ----------
__global__ __launch_bounds__(256) void self_attn(const float* __restrict__ qkv,
                                                 float* __restrict__ out) {
  const int wid = blockIdx.x * 4 + (threadIdx.x >> 6);
  const int lane = threadIdx.x & 63;
  const int bh = wid / 100, q = wid - bh * 100;
  const int b = bh >> 3, h = bh & 7;
  float4 qv[8];
  {
    const float4* qr = (const float4*)(qkv + (size_t)(b * 100 + q) * 768 + h * 32);
#pragma unroll
    for (int i = 0; i < 8; ++i) {
      float4 x = qr[i];
      qv[i] = make_float4(x.x * SCALE, x.y * SCALE, x.z * SCALE, x.w * SCALE);
    }
  }
  float l = 0.f;
  float4 O[8] = {};
  for (int k0 = 0; k0 < 128; k0 += 64) {
    int k = k0 + lane;
    int kc = (k < 100) ? k : 0;
    const float4* kr = (const float4*)(qkv + (size_t)(b * 100 + kc) * 768 + 256 + h * 32);
    float s = 0.f;
#pragma unroll
    for (int i = 0; i < 8; ++i) {
      float4 kx = kr[i];
      s += qv[i].x * kx.x + qv[i].y * kx.y + qv[i].z * kx.z + qv[i].w * kx.w;
    }
    float p = (k < 100) ? __expf(s) : 0.f;
    l += p;
    const float4* vr = (const float4*)(qkv + (size_t)(b * 100 + kc) * 768 + 512 + h * 32);
#pragma unroll
    for (int i = 0; i < 8; ++i) {
      float4 vx = vr[i];
      O[i].x += p * vx.x; O[i].y += p * vx.y; O[i].z += p * vx.z; O[i].w += p * vx.w;
    }
  }
#pragma unroll
  for (int off = 1; off < 64; off <<= 1) {
    l += __shfl_xor(l, off, 64);
#pragma unroll
    for (int i = 0; i < 8; ++i) {
      O[i].x += __shfl_xor(O[i].x, off, 64);
      O[i].y += __shfl_xor(O[i].y, off, 64);
      O[i].z += __shfl_xor(O[i].z, off, 64);
      O[i].w += __shfl_xor(O[i].w, off, 64);
    }
  }
  if (lane < 32) {
    float inv = 1.f / l;
    int i4 = lane >> 2, sub = lane & 3;
    float ov = 0.f;
#pragma unroll
    for (int i = 0; i < 8; ++i) {
      if (i4 == i) {
        float4 vv = O[i];
        ov = (sub == 0) ? vv.x : (sub == 1) ? vv.y : (sub == 2) ? vv.z : vv.w;
      }
    }
    out[(size_t)(b * 100 + q) * 256 + h * 32 + lane] = ov * inv;
  }
}

// ---------- fused KV-projection + masked cross-attention ----------
// grid 256 = (b 8) x (chunk 32: 512 keys); block 512 = 8 waves, wave = head.
// K never leaves registers: K-GEMM (A=Wk dims, B=pix keys) C-layout == S^T A-frag
// under k-slot perm sigma; Q loaded with matching sigma. V-GEMM (A=pix, B=Wv)
// C-layout == PV B-frag under perm pi matching P's A-slots.
__global__ __launch_bounds__(512, 2) void ca_fused(const float* __restrict__ qc,
                                                   const unsigned short* __restrict__ wkv,
                                                   const float* __restrict__ bkv,
                                                   const float* __restrict__ pix,
                                                   const unsigned char* __restrict__ mask,
                                                   unsigned short* __restrict__ Opartb,
                                                   float* __restrict__ lpart) {
  const int bid = blockIdx.x;
  const int b = bid >> 5, chunk = bid & 31;
  const int t = threadIdx.x;
  const int h = t >> 6, lane = t & 63, quad = lane >> 4, l16 = lane & 15;
  const int bh = b * 8 + h;

  __shared__ unsigned short PixS[8 * 32 * 40];

  frag8 qf[7];
#pragma unroll
  for (int qt = 0; qt < 7; ++qt) {
    int r = qt * 16 + l16;
    float4 f0 = {}, f1 = {};
    if (r < 100) {
      const float* qrow = qc + (size_t)(b * 100 + r) * 256 + h * 32 + quad * 4;
      f0 = *(const float4*)qrow;
      f1 = *(const float4*)(qrow + 16);
    }
    F8U u;
    u.u[0] = pack2(f0.x * SCALE2, f0.y * SCALE2);
    u.u[1] = pack2(f0.z * SCALE2, f0.w * SCALE2);
    u.u[2] = pack2(f1.x * SCALE2, f1.y * SCALE2);
    u.u[3] = pack2(f1.z * SCALE2, f1.w * SCALE2);
    qf[qt] = u.f;
  }

  float bK[2][4], bV[2];
#pragma unroll
  for (int mf = 0; mf < 2; ++mf) {
#pragma unroll
    for (int rg = 0; rg < 4; ++rg) bK[mf][rg] = bkv[h * 32 + mf * 16 + quad * 4 + rg];
    bV[mf] = bkv[256 + h * 32 + mf * 16 + l16];
  }

  const unsigned short* wkbase = wkv + (size_t)(h * 32) * 256;
  const unsigned short* wvbase = wkv + (size_t)(256 + h * 32) * 256;

  facc4 o[7][2] = {};
  float lacc[7] = {};
  const facc4 zacc = {0.f, 0.f, 0.f, 0.f};

  for (int it = 0; it < 16; ++it) {
    const int kk = it * 32;
    const int gkey = chunk * 512 + kk;
    __syncthreads();
    {
      int row = t >> 4, cg = (t & 15) * 16;
      const float* src = pix + ((size_t)(b * 16384 + gkey + row)) * 256 + cg;
      float4 a0 = *(const float4*)src;
      float4 a1 = *(const float4*)(src + 4);
      float4 a2 = *(const float4*)(src + 8);
      float4 a3 = *(const float4*)(src + 12);
      uint4 u0, u1;
      u0.x = tpack(a0.x, a0.y); u0.y = tpack(a0.z, a0.w);
      u0.z = tpack(a1.x, a1.y); u0.w = tpack(a1.z, a1.w);
      u1.x = tpack(a2.x, a2.y); u1.y = tpack(a2.z, a2.w);
      u1.z = tpack(a3.x, a3.y); u1.w = tpack(a3.z, a3.w);
      unsigned short* d = PixS + (cg >> 5) * 1280 + row * 40 + (cg & 31);
      *(uint4*)d = u0; *(uint4*)(d + 8) = u1;
    }
    __syncthreads();

    facc4 ka[2][2] = {}, va[2][2] = {};
#pragma unroll
    for (int cb = 0; cb < 8; ++cb) {
      frag8 pf0 = *(const frag8*)(PixS + cb * 1280 + l16 * 40 + quad * 8);
      frag8 pf1 = *(const frag8*)(PixS + cb * 1280 + (16 + l16) * 40 + quad * 8);
      int co = cb * 32 + quad * 8;
      frag8 wk0 = *(const frag8*)(wkbase + (size_t)l16 * 256 + co);
      frag8 wk1 = *(const frag8*)(wkbase + (size_t)(16 + l16) * 256 + co);
      frag8 wv0 = *(const frag8*)(wvbase + (size_t)l16 * 256 + co);
      frag8 wv1 = *(const frag8*)(wvbase + (size_t)(16 + l16) * 256 + co);
      ka[0][0] = MFMA16(wk0, pf0, ka[0][0]); ka[0][1] = MFMA16(wk0, pf1, ka[0][1]);
      ka[1][0] = MFMA16(wk1, pf0, ka[1][0]); ka[1][1] = MFMA16(wk1, pf1, ka[1][1]);
      va[0][0] = MFMA16(pf0, wv0, va[0][0]); va[0][1] = MFMA16(pf0, wv1, va[0][1]);
      va[1][0] = MFMA16(pf1, wv0, va[1][0]); va[1][1] = MFMA16(pf1, wv1, va[1][1]);
    }
    frag8 kfA0, kfA1, vfB0, vfB1;
    {
      F8U k0u, k1u, v0u, v1u;
#pragma unroll
      for (int pr = 0; pr < 4; ++pr) {
        int mf = pr >> 1, r0v = (pr & 1) * 2, r1v = r0v + 1;
        k0u.u[pr] = tpack(ka[mf][0][r0v] + bK[mf][r0v], ka[mf][0][r1v] + bK[mf][r1v]);
        k1u.u[pr] = tpack(ka[mf][1][r0v] + bK[mf][r0v], ka[mf][1][r1v] + bK[mf][r1v]);
        v0u.u[pr] = tpack(va[mf][0][r0v] + bV[0], va[mf][0][r1v] + bV[0]);
        v1u.u[pr] = tpack(va[mf][1][r0v] + bV[1], va[mf][1][r1v] + bV[1]);
      }
      kfA0 = k0u.f; kfA1 = k1u.f; vfB0 = v0u.f; vfB1 = v1u.f;
    }

    const unsigned char* mbase = mask + (size_t)bh * 100 * 16384 + gkey + quad * 4;
#pragma unroll
    for (int qt = 0; qt < 7; ++qt) {
      facc4 s0 = MFMA16(kfA0, qf[qt], zacc);
      facc4 s1 = MFMA16(kfA1, qf[qt], zacc);
      int r = qt * 16 + l16;
      int rc = (r < 100) ? r : 99;
      const unsigned char* mrow = mbase + (size_t)rc * 16384;
      unsigned m0 = *(const unsigned*)mrow;
      unsigned m1 = *(const unsigned*)(mrow + 16);
      if (r >= 100) { m0 = 0; m1 = 0; }
      float p[8];
#pragma unroll
      for (int rg = 0; rg < 4; ++rg) {
        float e0 = exp2f(s0[rg]);
        float e1 = exp2f(s1[rg]);
        p[rg] = ((m0 >> (rg * 8)) & 1u) ? e0 : 0.f;
        p[4 + rg] = ((m1 >> (rg * 8)) & 1u) ? e1 : 0.f;
      }
      lacc[qt] += p[0] + p[1] + p[2] + p[3] + p[4] + p[5] + p[6] + p[7];
      F8U pu;
      pu.u[0] = tpack(p[0], p[1]); pu.u[1] = tpack(p[2], p[3]);
      pu.u[2] = tpack(p[4], p[5]); pu.u[3] = tpack(p[6], p[7]);
      o[qt][0] = MFMA16(pu.f, vfB0, o[qt][0]);
      o[qt][1] = MFMA16(pu.f, vfB1, o[qt][1]);
    }
  }

#pragma unroll
  for (int qt = 0; qt < 7; ++qt) {
    lacc[qt] += __shfl_xor(lacc[qt], 16, 64);
    lacc[qt] += __shfl_xor(lacc[qt], 32, 64);
  }
  unsigned short* Op = Opartb + ((size_t)bh * 32 + chunk) * 112 * 32;
  float* lp = lpart + ((size_t)bh * 32 + chunk) * 112;
#pragma unroll
  for (int qt = 0; qt < 7; ++qt) {
#pragma unroll
    for (int rg = 0; rg < 4; ++rg) {
      int row = qt * 16 + quad * 4 + rg;
      Op[row * 32 + l16] = f2b(o[qt][0][rg]);
      Op[row * 32 + 16 + l16] = f2b(o[qt][1][rg]);
    }
    if (lane < 16) lp[qt * 16 + lane] = lacc[qt];
  }
}

// ---------- combine partials: out = sum(O) / sum(l) ----------
__global__ __launch_bounds__(256) void cross_combine(const unsigned short* __restrict__ Opartb,
                                                     const float* __restrict__ lpart,
                                                     float* __restrict__ out) {
  const int bid = blockIdx.x;
  const int bh = bid / 13, qg = bid - bh * 13;
  const int t = threadIdx.x;
  const int q = qg * 8 + (t >> 5), d = t & 31;
  if (q >= 100) return;
  const int b = bh >> 3, h = bh & 7;
  float osum = 0.f, lsum = 0.f;
#pragma unroll 4
  for (int p = 0; p < 32; ++p) {
    osum += b2f(Opartb[(((size_t)bh * 32 + p) * 112 + q) * 32 + d]);
    lsum += lpart[((size_t)bh * 32 + p) * 112 + q];
  }
  out[(size_t)(b * 100 + q) * 256 + h * 32 + d] = osum / lsum;
}

// ---------- host ----------
extern "C" void kernel_launch(void* const* d_in, const int* in_sizes, int n_in,
                              void* d_out, int out_size, void* d_ws, size_t ws_size,
                              hipStream_t stream) {
  const float* queries = (const float*)d_in[0];
  const float* pix = (const float*)d_in[1];
  const unsigned char* mask = (const unsigned char*)d_in[2];
  const float* sa_in_w = (const float*)d_in[3];
  const float* sa_in_b = (const float*)d_in[4];
  const float* sa_out_w = (const float*)d_in[5];
  const float* sa_out_b = (const float*)d_in[6];
  const float* n1g = (const float*)d_in[7];
  const float* n1b = (const float*)d_in[8];
  const float* ca_in_w = (const float*)d_in[9];
  const float* ca_in_b = (const float*)d_in[10];
  const float* ca_out_w = (const float*)d_in[11];
  const float* ca_out_b = (const float*)d_in[12];
  const float* n2g = (const float*)d_in[13];
  const float* n2b = (const float*)d_in[14];
  const float* ff_w1 = (const float*)d_in[15];
  const float* ff_b1 = (const float*)d_in[16];
  const float* ff_w2 = (const float*)d_in[17];
  const float* ff_b2 = (const float*)d_in[18];
  const float* n3g = (const float*)d_in[19];
  const float* n3b = (const float*)d_in[20];
  float* out = (float*)d_out;
  char* ws = (char*)d_ws;

  unsigned short* wb   = (unsigned short*)(ws + 134217728);    // 3145728
  float* qkvs   = (float*)(ws + 152043520);                    // 2457600
  float* sao    = (float*)(ws + 154501120);                    // 819200
  float* ptmp   = (float*)(ws + 155320320);                    // 3276800 (4 splitK partials)
  float* x1     = (float*)(ws + 158597120);                    // 819200
  float* qc     = (float*)(ws + 159416320);                    // 819200
  unsigned short* Opartb = (unsigned short*)(ws + 160235520);  // 14680064 (bf16)
  float* lpart  = (float*)(ws + 189595648);                    // 917504
  float* ca_out = (float*)(ws + 190513152);                    // 819200
  float* x2     = (float*)(ws + 191332352);                    // 819200
  float* hffn   = (float*)(ws + 192151552);                    // 6553600

  const unsigned short* wb_sain  = wb;
  const unsigned short* wb_saout = wb + 196608;
  const unsigned short* wb_caq   = wb + 262144;
  const unsigned short* wb_cakv  = wb + 327680;
  const unsigned short* wb_caout = wb + 458752;
  const unsigned short* wb_ff1   = wb + 524288;
  const unsigned short* wb_ff2   = wb + 1048576;

  cvt_weights<<<768, 256, 0, stream>>>(sa_in_w, sa_out_w, ca_in_w, ca_out_w, ff_w1, ff_w2, wb);

  // 1) self-attention block
  mfma_gemm<0, 1><<<dim3(13, 12, 1), 256, 0, stream>>>(queries, wb_sain, sa_in_b, qkvs, 800, 768, 256, 256);
  self_attn<<<1600, 256, 0, stream>>>(qkvs, sao);
  mfma_gemm<0, 1><<<dim3(13, 4, 1), 256, 0, stream>>>(sao, wb_saout, sa_out_b, ptmp, 800, 256, 256, 256);
  res_ln<<<800, 256, 0, stream>>>(ptmp, queries, n1g, n1b, x1);

  // 2) masked cross-attention block (fused KV-proj + attention)
  mfma_gemm<0, 1><<<dim3(13, 4, 1), 256, 0, stream>>>(x1, wb_caq, ca_in_b, qc, 800, 256, 256, 256);
  ca_fused<<<256, 512, 0, stream>>>(qc, wb_cakv, ca_in_b + 256, pix, mask, Opartb, lpart);
  cross_combine<<<64 * 13, 256, 0, stream>>>(Opartb, lpart, ca_out);
  mfma_gemm<0, 1><<<dim3(13, 4, 1), 256, 0, stream>>>(ca_out, wb_caout, ca_out_b, ptmp, 800, 256, 256, 256);
  res_ln<<<800, 256, 0, stream>>>(ptmp, x1, n2g, n2b, x2);

  // 3) FFN block
  mfma_gemm<1, 1><<<dim3(13, 32, 1), 256, 0, stream>>>(x2, wb_ff1, ff_b1, hffn, 800, 2048, 256, 256);
  mfma_gemm<0, 0><<<dim3(13, 4, 4), 256, 0, stream>>>(hffn, wb_ff2, nullptr, ptmp, 800, 256, 2048, 512);
  res_ln4<<<800, 256, 0, stream>>>(ptmp, ff_b2, x2, n3g, n3b, out);
}